// Round 1
// baseline (111.285 us; speedup 1.0000x reference)
//
#include <hip/hip_runtime.h>

// KDE KNN via spatial-hash bucketing.
// N=16384 points in [0,1)^3, sz=5 -> 125 cells, min_t_idx in [0,4).
// Valid buckets: b = y0*25+y1*5+y2 + min_t*125, min_t in {1,2,3} -> [125,500).
// Per valid point: K=16 smallest squared distances within its bucket
// (self included, d=0), kth -> r, out = pi*r^2 / 15 ; invalid -> 0.
// Bucket with <16 points -> kth = 1e10 sentinel (matches reference BIG).

#define KNN 16
#define NBUCKETS 512   // 500 used, padded to pow2 for the scan
#define BIGF 1e10f

__global__ void zero_counts_kernel(int* __restrict__ count) {
    count[threadIdx.x] = 0;
}

__global__ void bucketize_kernel(const float* __restrict__ x,
                                 const int* __restrict__ mt,
                                 int* __restrict__ bucket_of,
                                 int* __restrict__ count, int n) {
    int i = blockIdx.x * blockDim.x + threadIdx.x;
    if (i >= n) return;
    int m = mt[i];
    if (m > 0) {
        // trunc-toward-zero matches astype(int32); x in [0,1)
        int y0 = (int)(x[3 * i + 0] * 5.0f);
        int y1 = (int)(x[3 * i + 1] * 5.0f);
        int y2 = (int)(x[3 * i + 2] * 5.0f);
        int b = y0 * 25 + y1 * 5 + y2 + m * 125;
        bucket_of[i] = b;
        atomicAdd(&count[b], 1);
    } else {
        bucket_of[i] = -1;
    }
}

// single block of 512 threads: Hillis-Steele inclusive scan in LDS
__global__ void scan_counts_kernel(const int* __restrict__ count,
                                   int* __restrict__ start,
                                   int* __restrict__ cursor) {
    __shared__ int tmp[NBUCKETS];
    int t = threadIdx.x;
    int v = count[t];
    tmp[t] = v;
    __syncthreads();
    for (int off = 1; off < NBUCKETS; off <<= 1) {
        int u = (t >= off) ? tmp[t - off] : 0;
        __syncthreads();
        tmp[t] += u;
        __syncthreads();
    }
    int ex = tmp[t] - v;   // exclusive prefix
    start[t] = ex;
    cursor[t] = ex;
}

__global__ void scatter_kernel(const int* __restrict__ bucket_of,
                               int* __restrict__ cursor,
                               int* __restrict__ sorted, int n) {
    int i = blockIdx.x * blockDim.x + threadIdx.x;
    if (i >= n) return;
    int b = bucket_of[i];
    if (b >= 0) {
        int pos = atomicAdd(&cursor[b], 1);
        sorted[pos] = i;
    }
}

__global__ void knn_kernel(const float* __restrict__ x,
                           const int* __restrict__ bucket_of,
                           const int* __restrict__ start,
                           const int* __restrict__ count,
                           const int* __restrict__ sorted,
                           float* __restrict__ out, int n) {
    int i = blockIdx.x * blockDim.x + threadIdx.x;
    if (i >= n) return;
    int b = bucket_of[i];
    if (b < 0) { out[i] = 0.0f; return; }

    float xi0 = x[3 * i + 0];
    float xi1 = x[3 * i + 1];
    float xi2 = x[3 * i + 2];

    int s = start[b];
    int e = s + count[b];

    // register top-K (smallest K squared distances); sentinel-filled so
    // deficient buckets (<K members) reproduce the reference's BIG path.
    float best[KNN];
#pragma unroll
    for (int k = 0; k < KNN; ++k) best[k] = BIGF;
    float curmax = BIGF;
    int maxpos = 0;

    for (int t = s; t < e; ++t) {
        int j = sorted[t];
        float dx = xi0 - x[3 * j + 0];
        float dy = xi1 - x[3 * j + 1];
        float dz = xi2 - x[3 * j + 2];
        float d2 = dx * dx + dy * dy + dz * dz;
        if (d2 < curmax) {
            // predicated writes keep best[] in VGPRs (no runtime indexing)
#pragma unroll
            for (int k = 0; k < KNN; ++k)
                if (k == maxpos) best[k] = d2;
            curmax = best[0]; maxpos = 0;
#pragma unroll
            for (int k = 1; k < KNN; ++k) {
                if (best[k] > curmax) { curmax = best[k]; maxpos = k; }
            }
        }
    }

    // kth smallest = max of retained K; reference: r = sqrt(max(kth,0)),
    // vol = pi*r^2 (dim = NI-1 = 2), out = vol/(K-1)
    float r2 = fmaxf(curmax, 0.0f);
    float r = sqrtf(r2);
    float vol = 3.14159265358979323846f * r * r;
    out[i] = vol / 15.0f;
}

extern "C" void kernel_launch(void* const* d_in, const int* in_sizes, int n_in,
                              void* d_out, int out_size, void* d_ws, size_t ws_size,
                              hipStream_t stream) {
    const float* x  = (const float*)d_in[0];
    const int*   mt = (const int*)d_in[1];
    // d_in[2] = K (16), d_in[3] = sz (5) -- compile-time constants here
    float* out = (float*)d_out;
    int n = in_sizes[1];

    char* ws = (char*)d_ws;
    int* count     = (int*)(ws + 0);
    int* start     = (int*)(ws + 2048);
    int* cursor    = (int*)(ws + 4096);
    int* bucket_of = (int*)(ws + 6144);
    int* sorted    = (int*)(ws + 6144 + sizeof(int) * (size_t)n);

    int blocks = (n + 255) / 256;
    zero_counts_kernel<<<1, NBUCKETS, 0, stream>>>(count);
    bucketize_kernel<<<blocks, 256, 0, stream>>>(x, mt, bucket_of, count, n);
    scan_counts_kernel<<<1, NBUCKETS, 0, stream>>>(count, start, cursor);
    scatter_kernel<<<blocks, 256, 0, stream>>>(bucket_of, cursor, sorted, n);
    knn_kernel<<<blocks, 256, 0, stream>>>(x, bucket_of, start, count, sorted, out, n);
}

// Round 2
// 102.303 us; speedup vs baseline: 1.0878x; 1.0878x over previous
//
#include <hip/hip_runtime.h>

// KDE KNN via spatial-hash bucketing, 2-kernel version.
//
// Kernel 1 (single block, 1024 thr): bucketize + LDS histogram + LDS scan +
//   counting-sort scatter. Emits, per valid point in bucket-sorted order:
//     xs[slot]    = float4(x0,x1,x2, bitcast(point_id))
//     range[slot] = int2(bucket_start, bucket_end)   (slot range in xs)
//   and writes out[i]=0 for invalid (min_t_idx==0) points.
//
// Kernel 2: thread t handles sorted slot t. All lanes of a wave share a
//   bucket (sorted order) -> coherent trip counts, broadcast float4 loads,
//   no indirection. Register top-16, sentinel 1e10 for deficient buckets.

#define KNN 16
#define NB 512          // 500 buckets used (125 cells x min_t in {1,2,3})
#define BIGF 1e10f
#define SORT_THREADS 1024

__global__ __launch_bounds__(SORT_THREADS) void sort_kernel(
    const float* __restrict__ x, const int* __restrict__ mt,
    float4* __restrict__ xs, int2* __restrict__ range,
    int* __restrict__ total, float* __restrict__ out, int n)
{
    __shared__ int hist[NB];
    __shared__ int scanb[NB];
    __shared__ int cursor[NB];
    const int t = threadIdx.x;
    if (t < NB) hist[t] = 0;
    __syncthreads();

    const int PPT = 16;           // 16384 / 1024
    int   mybb[PPT];
    float myx[PPT], myy[PPT], myz[PPT];
#pragma unroll
    for (int p = 0; p < PPT; ++p) {
        int i = p * SORT_THREADS + t;
        int b = -1;
        float x0 = 0.f, x1 = 0.f, x2 = 0.f;
        if (i < n) {
            int m = mt[i];
            x0 = x[3 * i + 0]; x1 = x[3 * i + 1]; x2 = x[3 * i + 2];
            if (m > 0) {
                // trunc-toward-zero == astype(int32); x in [0,1)
                int y0 = (int)(x0 * 5.0f);
                int y1 = (int)(x1 * 5.0f);
                int y2 = (int)(x2 * 5.0f);
                b = y0 * 25 + y1 * 5 + y2 + m * 125;
                atomicAdd(&hist[b], 1);
            } else {
                out[i] = 0.0f;    // invalid points: reference outputs 0
            }
        }
        mybb[p] = b; myx[p] = x0; myy[p] = x1; myz[p] = x2;
    }
    __syncthreads();

    // Hillis-Steele inclusive scan of hist -> scanb (512 entries)
    if (t < NB) scanb[t] = hist[t];
    __syncthreads();
    for (int off = 1; off < NB; off <<= 1) {
        int u = (t < NB && t >= off) ? scanb[t - off] : 0;
        __syncthreads();
        if (t < NB) scanb[t] += u;
        __syncthreads();
    }
    if (t == NB - 1) total[0] = scanb[NB - 1];   // total valid points
    int ex = 0;
    if (t < NB) ex = scanb[t] - hist[t];          // exclusive prefix
    __syncthreads();
    if (t < NB) { scanb[t] = ex; cursor[t] = ex; }
    __syncthreads();

    // counting-sort scatter: x values + id into bucket-sorted float4 array
#pragma unroll
    for (int p = 0; p < PPT; ++p) {
        int b = mybb[p];
        if (b >= 0) {
            int i = p * SORT_THREADS + t;
            int pos = atomicAdd(&cursor[b], 1);
            xs[pos] = make_float4(myx[p], myy[p], myz[p], __int_as_float(i));
            int s = scanb[b];
            range[pos] = make_int2(s, s + hist[b]);
        }
    }
}

__global__ __launch_bounds__(64) void knn_kernel(
    const float4* __restrict__ xs, const int2* __restrict__ range,
    const int* __restrict__ total, float* __restrict__ out)
{
    int t = blockIdx.x * blockDim.x + threadIdx.x;
    if (t >= *total) return;

    float4 p = xs[t];
    int2 se = range[t];

    float best[KNN];
#pragma unroll
    for (int k = 0; k < KNN; ++k) best[k] = BIGF;
    float curmax = BIGF;
    int maxpos = 0;

    for (int u = se.x; u < se.y; ++u) {
        float4 q = xs[u];                 // broadcast across wave (same bucket)
        float dx = p.x - q.x;
        float dy = p.y - q.y;
        float dz = p.z - q.z;
        float d2 = dx * dx + dy * dy + dz * dz;
        if (d2 < curmax) {
            // predicated writes keep best[] in VGPRs (no runtime indexing)
#pragma unroll
            for (int k = 0; k < KNN; ++k)
                if (k == maxpos) best[k] = d2;
            curmax = best[0]; maxpos = 0;
#pragma unroll
            for (int k = 1; k < KNN; ++k)
                if (best[k] > curmax) { curmax = best[k]; maxpos = k; }
        }
    }

    int i = __float_as_int(p.w);
    float r = sqrtf(fmaxf(curmax, 0.0f));   // kth smallest incl. self (d=0)
    float vol = 3.14159265358979323846f * r * r;   // dim = NI-1 = 2
    out[i] = vol / 15.0f;                   // /(K-1)
}

extern "C" void kernel_launch(void* const* d_in, const int* in_sizes, int n_in,
                              void* d_out, int out_size, void* d_ws, size_t ws_size,
                              hipStream_t stream) {
    const float* x  = (const float*)d_in[0];
    const int*   mt = (const int*)d_in[1];
    float* out = (float*)d_out;
    int n = in_sizes[1];

    char* ws = (char*)d_ws;
    float4* xs    = (float4*)(ws + 0);                        // n*16 B
    int2*   range = (int2*)(ws + (size_t)n * 16);             // n*8 B
    int*    total = (int*)(ws + (size_t)n * 24);              // 4 B

    sort_kernel<<<1, SORT_THREADS, 0, stream>>>(x, mt, xs, range, total, out, n);
    int blocks = (n + 63) / 64;
    knn_kernel<<<blocks, 64, 0, stream>>>(xs, range, total, out);
}

// Round 4
// 96.844 us; speedup vs baseline: 1.1491x; 1.0564x over previous
//
#include <hip/hip_runtime.h>

// KDE KNN via spatial-hash bucketing — fully parallel counting sort.
//
// memset(4KB): count[512]+cursor[512] = 0
// hist    (64x256): b = y0*25+y1*5+y2 + mt*125 (mt>0), atomicAdd count[b];
//                   out[i]=0 for invalid points; bucket_of[i] stored.
// scatter (64x256): per-block LDS scan of count (512 bins, replicated),
//                   pos = excl[b] + atomicAdd(cursor[b],1),
//                   xs[pos]=float4(x,id), range[pos]=(start,end); block 0
//                   writes total (= #valid points).
// knn     (64x256): thread t = sorted slot t (t < total). Wave-coherent
//                   bucket walk, broadcast float4 loads, register top-16.
//                   Deficient buckets (<16) keep the 1e10 sentinel == ref BIG.

#define KNN 16
#define NB 512          // 500 used (125 cells x mt in {1,2,3})
#define BIGF 1e10f

__global__ __launch_bounds__(256) void hist_kernel(
    const float* __restrict__ x, const int* __restrict__ mt,
    int* __restrict__ count, int* __restrict__ bucket_of,
    float* __restrict__ out, int n)
{
    int i = blockIdx.x * blockDim.x + threadIdx.x;
    if (i >= n) return;
    int m = mt[i];
    int b = -1;
    if (m > 0) {
        // trunc-toward-zero == astype(int32); x in [0,1)
        int y0 = (int)(x[3 * i + 0] * 5.0f);
        int y1 = (int)(x[3 * i + 1] * 5.0f);
        int y2 = (int)(x[3 * i + 2] * 5.0f);
        b = y0 * 25 + y1 * 5 + y2 + m * 125;
        atomicAdd(&count[b], 1);
    } else {
        out[i] = 0.0f;
    }
    bucket_of[i] = b;
}

__global__ __launch_bounds__(256) void scatter_kernel(
    const float* __restrict__ x, const int* __restrict__ bucket_of,
    const int* __restrict__ count, int* __restrict__ cursor,
    float4* __restrict__ xs, int2* __restrict__ range,
    int* __restrict__ total, int n)
{
    __shared__ int incl[NB];   // inclusive scan
    __shared__ int excl[NB];   // exclusive scan
    const int t = threadIdx.x;

    // replicated per-block scan of the 512-bin histogram (2 entries/thread)
    int o0 = count[t];
    int o1 = count[t + 256];
    incl[t] = o0; incl[t + 256] = o1;
    __syncthreads();
    for (int off = 1; off < NB; off <<= 1) {
        int v0 = (t >= off) ? incl[t - off] : 0;
        int v1 = (t + 256 >= off) ? incl[t + 256 - off] : 0;
        __syncthreads();
        incl[t] += v0; incl[t + 256] += v1;
        __syncthreads();
    }
    excl[t] = incl[t] - o0;
    excl[t + 256] = incl[t + 256] - o1;
    __syncthreads();

    if (blockIdx.x == 0 && t == 255) total[0] = incl[NB - 1];

    int i = blockIdx.x * blockDim.x + t;
    if (i >= n) return;
    int b = bucket_of[i];
    if (b < 0) return;
    int pos = excl[b] + atomicAdd(&cursor[b], 1);
    xs[pos] = make_float4(x[3 * i + 0], x[3 * i + 1], x[3 * i + 2],
                          __int_as_float(i));
    range[pos] = make_int2(excl[b], incl[b]);
}

__global__ __launch_bounds__(256) void knn_kernel(
    const float4* __restrict__ xs, const int2* __restrict__ range,
    const int* __restrict__ total, float* __restrict__ out)
{
    int t = blockIdx.x * blockDim.x + threadIdx.x;
    if (t >= *total) return;

    float4 p = xs[t];
    int2 se = range[t];

    float best[KNN];
#pragma unroll
    for (int k = 0; k < KNN; ++k) best[k] = BIGF;
    float curmax = BIGF;
    int maxpos = 0;

    for (int u = se.x; u < se.y; ++u) {
        float4 q = xs[u];        // broadcast across wave (shared bucket)
        float dx = p.x - q.x;
        float dy = p.y - q.y;
        float dz = p.z - q.z;
        float d2 = dx * dx + dy * dy + dz * dz;
        if (d2 < curmax) {
            // predicated writes keep best[] in VGPRs (no runtime indexing)
#pragma unroll
            for (int k = 0; k < KNN; ++k)
                if (k == maxpos) best[k] = d2;
            curmax = best[0]; maxpos = 0;
#pragma unroll
            for (int k = 1; k < KNN; ++k)
                if (best[k] > curmax) { curmax = best[k]; maxpos = k; }
        }
    }

    int i = __float_as_int(p.w);
    float r = sqrtf(fmaxf(curmax, 0.0f));          // kth smallest incl. self
    float vol = 3.14159265358979323846f * r * r;   // dim = NI-1 = 2
    out[i] = vol / 15.0f;                          // /(K-1)
}

extern "C" void kernel_launch(void* const* d_in, const int* in_sizes, int n_in,
                              void* d_out, int out_size, void* d_ws, size_t ws_size,
                              hipStream_t stream) {
    const float* x  = (const float*)d_in[0];
    const int*   mt = (const int*)d_in[1];
    float* out = (float*)d_out;
    int n = in_sizes[1];

    char* ws = (char*)d_ws;
    int*    count     = (int*)(ws + 0);            // 2 KB
    int*    cursor    = (int*)(ws + 2048);         // 2 KB
    int*    total     = (int*)(ws + 4096);         // 4 B
    int*    bucket_of = (int*)(ws + 8192);         // n*4
    float4* xs        = (float4*)(ws + 8192 + (size_t)n * 4);        // n*16
    int2*   range     = (int2*)(ws + 8192 + (size_t)n * 20);         // n*8

    hipMemsetAsync(ws, 0, 4096, stream);           // count + cursor
    int blocks = (n + 255) / 256;
    hist_kernel<<<blocks, 256, 0, stream>>>(x, mt, count, bucket_of, out, n);
    scatter_kernel<<<blocks, 256, 0, stream>>>(x, bucket_of, count, cursor,
                                               xs, range, total, n);
    knn_kernel<<<blocks, 256, 0, stream>>>(xs, range, total, out);
}